// Round 1
// baseline (87.278 us; speedup 1.0000x reference)
//
#include <hip/hip_runtime.h>
#include <stdint.h>

#define Bb 32
#define Nn 256
#define Ee 8
#define Ff 16
#define K1 32

typedef unsigned long long u64;

// Kernel A: adjacency floats -> 256-bit row bitmasks. One wave per (b,r).
__global__ void bitmask_kernel(const float* __restrict__ adj, u64* __restrict__ bm) {
    int wave = (blockIdx.x << 2) + (threadIdx.x >> 6);   // (b*N + r), 4 waves/block
    int lane = threadIdx.x & 63;
    const float* row = adj + (size_t)wave * Nn;
#pragma unroll
    for (int w = 0; w < 4; ++w) {
        float v = row[w * 64 + lane];
        u64 m = __ballot(v != 0.0f);
        if (lane == 0) bm[(size_t)wave * 4 + w] = m;
    }
}

// Kernel B: per-thread BFS (one block per batch, thread = start vertex).
__global__ void bfs_kernel(const u64* __restrict__ bm, uint32_t* __restrict__ proc32) {
    __shared__ u64 bml[Nn * 4];          // 8 KB: bitmask rows for this batch
    __shared__ uint8_t order[Nn * K1];   // 8 KB: BFS order per start
    int b = blockIdx.x;
    int t = threadIdx.x;
#pragma unroll
    for (int k = 0; k < 4; ++k) bml[t + k * 256] = bm[(size_t)b * 1024 + t + k * 256];
    uint32_t* ord32 = (uint32_t*)order;
#pragma unroll
    for (int k = 0; k < 8; ++k) ord32[t + k * 256] = 0;
    __syncthreads();

    int s = t;
    u64 seen[4];
#pragma unroll
    for (int w = 0; w < 4; ++w) seen[w] = (w == (s >> 6)) ? (1ull << (s & 63)) : 0ull;
    order[s * K1] = (uint8_t)s;
    int count = 1;
    for (int i = 0; i < count && count < K1; ++i) {
        int cur = order[s * K1 + i];
#pragma unroll
        for (int w = 0; w < 4; ++w) {
            u64 nw = bml[cur * 4 + w] & ~seen[w];
            seen[w] |= nw;   // mark all new neighbours seen (extras past 32 are harmless)
            while (nw) {
                int bit = __builtin_ctzll(nw);
                nw &= nw - 1;
                if (count < K1) order[s * K1 + count++] = (uint8_t)(w * 64 + bit);
                else break;
            }
        }
    }
    __syncthreads();
    // coalesced writeout: LDS byte layout == global proc byte layout within block
#pragma unroll
    for (int k = 0; k < 8; ++k) proc32[(size_t)b * 2048 + t + k * 256] = ord32[t + k * 256];
}

// Kernel C: gather all three outputs. One block per (b,s).
__global__ void gather_kernel(const float4* __restrict__ e4,
                              const float4* __restrict__ feats4,
                              const u64* __restrict__ bm,
                              const uint32_t* __restrict__ proc32,
                              float* __restrict__ out) {
    int bs = blockIdx.x;
    int b = bs >> 8;
    int t = threadIdx.x;
    __shared__ int p[K1];
    __shared__ u64 bmrow[K1][4];

    if (t < 8) {
        uint32_t w = proc32[(size_t)bs * 8 + t];
        p[t * 4 + 0] = w & 255;
        p[t * 4 + 1] = (w >> 8) & 255;
        p[t * 4 + 2] = (w >> 16) & 255;
        p[t * 4 + 3] = (w >> 24) & 255;
    }
    __syncthreads();
    if (t < 128) {
        int i = t >> 2, w = t & 3;
        bmrow[i][w] = bm[((size_t)b * 256 + p[i]) * 4 + w];
    }
    __syncthreads();

    // ---- sub_adj: (K1,K1) floats, 256 float4 per block ----
    float4* out0 = (float4*)(out) + (size_t)bs * 256;
    {
        int i = t >> 3;
        int j0 = (t & 7) * 4;
        float4 a;
        int pj;
        pj = p[j0 + 0]; a.x = (float)((bmrow[i][pj >> 6] >> (pj & 63)) & 1ull);
        pj = p[j0 + 1]; a.y = (float)((bmrow[i][pj >> 6] >> (pj & 63)) & 1ull);
        pj = p[j0 + 2]; a.z = (float)((bmrow[i][pj >> 6] >> (pj & 63)) & 1ull);
        pj = p[j0 + 3]; a.w = (float)((bmrow[i][pj >> 6] >> (pj & 63)) & 1ull);
        out0[t] = a;
    }

    // ---- sub_feats: (K1,F) floats, 128 float4 per block ----
    float4* out2 = (float4*)(out + 75497472ull) + (size_t)bs * 128;
    if (t < 128) {
        int i = t >> 2, f4 = t & 3;
        out2[t] = feats4[((size_t)b * 256 + p[i]) * 4 + f4];
    }

    // ---- sub_edges: (K1,K1,E) floats, 2048 float4 per block ----
    float4* out1 = (float4*)(out + 8388608ull) + (size_t)bs * 2048;
#pragma unroll
    for (int k = 0; k < 8; ++k) {
        int v = t + k * 256;
        int i = v >> 6, j = (v >> 1) & 31, h = v & 1;
        int pi = p[i], pj = p[j];
        bool m = (bmrow[i][pj >> 6] >> (pj & 63)) & 1ull;
        float4 val = make_float4(0.f, 0.f, 0.f, 0.f);
        if (m) val = e4[(((size_t)b * 256 + pi) * 256 + pj) * 2 + h];
        out1[v] = val;
    }
}

extern "C" void kernel_launch(void* const* d_in, const int* in_sizes, int n_in,
                              void* d_out, int out_size, void* d_ws, size_t ws_size,
                              hipStream_t stream) {
    const float* adj   = (const float*)d_in[0];
    const float* edges = (const float*)d_in[1];
    const float* feats = (const float*)d_in[2];
    float* out = (float*)d_out;

    u64* bm = (u64*)d_ws;                                          // 262144 B
    uint32_t* proc32 = (uint32_t*)((char*)d_ws + (size_t)Bb * Nn * 4 * sizeof(u64));

    bitmask_kernel<<<Bb * Nn / 4, 256, 0, stream>>>(adj, bm);
    bfs_kernel<<<Bb, 256, 0, stream>>>(bm, proc32);
    gather_kernel<<<Bb * Nn, 256, 0, stream>>>((const float4*)edges, (const float4*)feats,
                                               bm, proc32, out);
}